// Round 3
// baseline (101.287 us; speedup 1.0000x reference)
//
#include <hip/hip_runtime.h>
#include <hip/hip_bf16.h>

// out[i, :] = emb[ids[i], :]  — the reference's sort/gather/inverse-sort is the identity.
// ids: [524288] int32, emb: [1M, 128] f32 (512 MB), out: [524288, 128] f32 (256 MB).
//
// 32 lanes per row, one 16B vector per lane -> coalesced 512B row copies.
// Each half-wave handles 4 rows (strided) for 4 independent gathers in
// flight per thread (MLP); output stores are nontemporal so the 256 MB
// write stream doesn't evict emb rows from L2/L3 (duplicate-id reads ~21%).

#define EMB 128
#define ROWS_PER_HW 4

typedef float f32x4 __attribute__((ext_vector_type(4)));  // native vector: OK for nontemporal builtins

__global__ void __launch_bounds__(256)
TFDistributedEmbedding_76828374991710_kernel(const int* __restrict__ ids,
                                             const float* __restrict__ emb,
                                             float* __restrict__ out,
                                             int n_ids) {
    int gtid = blockIdx.x * blockDim.x + threadIdx.x;
    int hw   = gtid >> 5;          // half-wave index (32 lanes per row)
    int lane = gtid & 31;
    int H    = (gridDim.x * blockDim.x) >> 5;  // total half-waves in grid

    int rows[ROWS_PER_HW];
    int idv[ROWS_PER_HW];
#pragma unroll
    for (int k = 0; k < ROWS_PER_HW; ++k) {
        int r = hw + k * H;
        rows[k] = r;
        idv[k] = (r < n_ids) ? __builtin_nontemporal_load(&ids[r]) : 0;
    }

    f32x4 v[ROWS_PER_HW];
#pragma unroll
    for (int k = 0; k < ROWS_PER_HW; ++k) {
        const f32x4* __restrict__ src =
            reinterpret_cast<const f32x4*>(emb + (long long)idv[k] * EMB);
        v[k] = src[lane];          // 4 independent dwordx4 gathers in flight
    }

#pragma unroll
    for (int k = 0; k < ROWS_PER_HW; ++k) {
        if (rows[k] < n_ids) {
            f32x4* __restrict__ dst =
                reinterpret_cast<f32x4*>(out + (long long)rows[k] * EMB);
            __builtin_nontemporal_store(v[k], &dst[lane]);
        }
    }
}

extern "C" void kernel_launch(void* const* d_in, const int* in_sizes, int n_in,
                              void* d_out, int out_size, void* d_ws, size_t ws_size,
                              hipStream_t stream) {
    const int*   ids = (const int*)d_in[0];     // [8, 65536] int32
    const float* emb = (const float*)d_in[1];   // [1M, 128] f32
    float*       out = (float*)d_out;           // [8, 65536, 128] f32

    int n_ids = in_sizes[0];                    // 524288
    long long lane_items = (long long)n_ids * 32;         // one lane-item = 16B
    long long total_threads = (lane_items + ROWS_PER_HW - 1) / ROWS_PER_HW;
    int block = 256;
    int grid = (int)((total_threads + block - 1) / block);

    TFDistributedEmbedding_76828374991710_kernel<<<grid, block, 0, stream>>>(ids, emb, out, n_ids);
}